// Round 3
// baseline (415.486 us; speedup 1.0000x reference)
//
#include <hip/hip_runtime.h>
#include <math.h>

// GumbelQuantizer: out[n,g,:] = emb[argmax_c(logits[n,g,c] + gumbels[n,g,c])]
// (straight-through forward == hard one-hot; softmax/TAU are argmax-invariant).
// fp16-MFMA fast path + margin-flagged fp64 exact refine for near-ties.
// R3: explicit double-buffered register prefetch of weight fragments in both
// k-loops (latency was unhidden: MfmaUtil 9%, 2 waves/SIMD, no compiler pipelining).

#define NTOK   32768   // BS*L
#define DIM    512
#define INNER  1024
#define NC     320
#define NGRP   2
#define VD     128
#define OUTD   256
#define RCAP   2048            // refine list capacity (expected ~520 flagged)
#define W1T_OFF (1u<<19)       // ws byte offsets
#define W2T_OFF (1u<<21)
#define HD_OFF  (1u<<22)       // fp32 h rows for flagged entries (RCAP*4KB = 8MB)
#define MARGIN 8.0e-3f         // ~4x estimated max fp16-path logit error
#define SMEM_BYTES (131072 + 6144 + 512)

typedef _Float16 half8 __attribute__((ext_vector_type(8)));
typedef _Float16 half4 __attribute__((ext_vector_type(4)));
typedef float    f32x4 __attribute__((ext_vector_type(4)));

// ---------------------------------------------------------------- prep:
__global__ void prep_kernel(const float* __restrict__ W1, const float* __restrict__ W2,
                            _Float16* __restrict__ W1T, _Float16* __restrict__ W2T,
                            unsigned* __restrict__ cnt) {
  if (blockIdx.x == 0 && threadIdx.x == 0) cnt[0] = 0u;
  const int col = blockIdx.x;
  const int t = threadIdx.x;
  if (col < INNER) {
    for (int k = t; k < DIM; k += 256)
      W1T[(size_t)col * DIM + k] = (_Float16)W1[(size_t)k * INNER + col];
  } else {
    const int c = col - INNER;  // 0..639
    for (int k = t; k < INNER; k += 256)
      W2T[(size_t)c * INNER + k] = (_Float16)W2[(size_t)k * (NC * NGRP) + c];
  }
}

__device__ __forceinline__ float gelu_f(float s) {
  return 0.5f * s * (1.0f + erff(s * 0.70710678118654752440f));
}

// ---------------------------------------------------------------- fused:
// one block = 64 tokens, 8 waves (512 thr).
// LDS: [0,64K)   x tile fp16 [64][512], row-swizzled (phase 1 B operand)
//      [0,128K)  h tile fp16 [64][1024], row-swizzled (overwrites x after GEMM1)
//      [128K..)  reduction scratch + idx
__global__ __launch_bounds__(512, 2)
void fused_kernel(const float* __restrict__ x, const float* __restrict__ gum,
                  const _Float16* __restrict__ W1T, const _Float16* __restrict__ W2T,
                  const float* __restrict__ b1, const float* __restrict__ b2,
                  const float* __restrict__ emb, float* __restrict__ out,
                  unsigned* __restrict__ cnt, unsigned* __restrict__ list) {
  extern __shared__ char smem[];
  float*    redm1 = (float*)(smem + 131072);
  float*    redm2 = (float*)(smem + 131072 + 2048);
  unsigned* redi  = (unsigned*)(smem + 131072 + 4096);
  unsigned* idxs  = (unsigned*)(smem + 131072 + 6144);

  const int tid = threadIdx.x;
  const int w   = tid >> 6;
  const int l   = tid & 63;
  const int l15 = l & 15;
  const int lq  = l >> 4;
  const int T0  = blockIdx.x << 6;
  const unsigned xmask = (unsigned)((l15 & 7) << 4);  // token&7 == l15&7 (nt*16 ≡ 0 mod 8... mod 16)

  // ---- stage x (64 x 512 fp32 -> fp16, swizzled, row stride 1024B)
#pragma unroll
  for (int i = 0; i < 16; ++i) {
    const int q = tid + i * 512;          // 0..8191 float4 slots
    const int row = q >> 7;
    const int c = (q & 127) << 2;
    const float4 v = *(const float4*)(x + (size_t)(T0 + row) * DIM + c);
    half4 hv; hv[0] = (_Float16)v.x; hv[1] = (_Float16)v.y;
    hv[2] = (_Float16)v.z; hv[3] = (_Float16)v.w;
    const unsigned byte = ((unsigned)(row * 1024 + c * 2)) ^ ((unsigned)(row & 7) << 4);
    *(half4*)(smem + byte) = hv;
  }
  __syncthreads();

  // ---- Phase 1: h = gelu(x @ W1 + b1). Wave w owns inner slice [w*128, w*128+128).
  {
    f32x4 acc[8][4];
#pragma unroll
    for (int i = 0; i < 8; ++i)
#pragma unroll
      for (int j = 0; j < 4; ++j) { f32x4 z = {0.f,0.f,0.f,0.f}; acc[i][j] = z; }

    const _Float16* w1p = W1T + (size_t)(w * 128 + l15) * DIM + lq * 8;

#define LD_A1(dst, ks) \
    _Pragma("unroll") for (int mt = 0; mt < 8; ++mt) \
      dst[mt] = *(const half8*)(w1p + (size_t)(mt * 16) * DIM + (ks) * 32);
#define LD_B1(dst, ks) \
    _Pragma("unroll") for (int nt = 0; nt < 4; ++nt) { \
      const unsigned byte = ((unsigned)((nt * 16 + l15) * 1024 + (ks) * 64 + lq * 16)) ^ xmask; \
      dst[nt] = *(const half8*)(smem + byte); }
#define MM1(aa, bb) \
    _Pragma("unroll") for (int mt = 0; mt < 8; ++mt) \
      _Pragma("unroll") for (int nt = 0; nt < 4; ++nt) \
        acc[mt][nt] = __builtin_amdgcn_mfma_f32_16x16x32_f16(aa[mt], bb[nt], acc[mt][nt], 0, 0, 0);

    half8 A0[8], A1[8], B0[4], B1[4];
    LD_A1(A0, 0) LD_B1(B0, 0)
#pragma unroll
    for (int kk = 0; kk < 8; ++kk) {
      LD_A1(A1, 2 * kk + 1) LD_B1(B1, 2 * kk + 1)
      MM1(A0, B0)
      if (kk < 7) { LD_A1(A0, 2 * kk + 2) LD_B1(B0, 2 * kk + 2) }
      MM1(A1, B1)
    }
#undef LD_A1
#undef LD_B1
#undef MM1
    __syncthreads();  // all waves done reading x tile

    // epilogue: +b1, exact-erf GELU, fp16 -> h LDS [64][1024], row-swizzled (2048B rows)
#pragma unroll
    for (int mt = 0; mt < 8; ++mt) {
      const int inner0 = w * 128 + mt * 16 + lq * 4;
      const float4 bv = *(const float4*)(b1 + inner0);
#pragma unroll
      for (int nt = 0; nt < 4; ++nt) {
        const int token = nt * 16 + l15;
        const f32x4 v = acc[mt][nt];
        half4 hv;
        hv[0] = (_Float16)gelu_f(v[0] + bv.x);
        hv[1] = (_Float16)gelu_f(v[1] + bv.y);
        hv[2] = (_Float16)gelu_f(v[2] + bv.z);
        hv[3] = (_Float16)gelu_f(v[3] + bv.w);
        const unsigned byte = ((unsigned)(token * 2048 + inner0 * 2))
                              ^ ((unsigned)(token & 7) << 4);
        *(half4*)(smem + byte) = hv;
      }
    }
  }
  __syncthreads();

  // ---- Phase 2: logits = h @ W2 + b2 + gumbels; top-2 per (token,group).
  const int g = w >> 2;
  {
    f32x4 acc[5][4];
#pragma unroll
    for (int i = 0; i < 5; ++i)
#pragma unroll
      for (int j = 0; j < 4; ++j) { f32x4 z = {0.f,0.f,0.f,0.f}; acc[i][j] = z; }

    const _Float16* w2p = W2T + (size_t)(w * 80 + l15) * INNER + lq * 8;

#define LD_A2(dst, ks) \
    _Pragma("unroll") for (int mt = 0; mt < 5; ++mt) \
      dst[mt] = *(const half8*)(w2p + (size_t)(mt * 16) * INNER + (ks) * 32);
#define LD_B2(dst, ks) \
    _Pragma("unroll") for (int nt = 0; nt < 4; ++nt) { \
      const unsigned byte = ((unsigned)((nt * 16 + l15) * 2048 + (ks) * 64 + lq * 16)) ^ xmask; \
      dst[nt] = *(const half8*)(smem + byte); }
#define MM2(aa, bb) \
    _Pragma("unroll") for (int mt = 0; mt < 5; ++mt) \
      _Pragma("unroll") for (int nt = 0; nt < 4; ++nt) \
        acc[mt][nt] = __builtin_amdgcn_mfma_f32_16x16x32_f16(aa[mt], bb[nt], acc[mt][nt], 0, 0, 0);

    half8 A0[5], A1[5], B0[4], B1[4];
    LD_A2(A0, 0) LD_B2(B0, 0)
#pragma unroll
    for (int kk = 0; kk < 16; ++kk) {
      LD_A2(A1, 2 * kk + 1) LD_B2(B1, 2 * kk + 1)
      MM2(A0, B0)
      if (kk < 15) { LD_A2(A0, 2 * kk + 2) LD_B2(B0, 2 * kk + 2) }
      MM2(A1, B1)
    }
#undef LD_A2
#undef LD_B2
#undef MM2

    // per-lane top-2 (ascending code order -> first-index tie-break like np.argmax)
    float m1v[4] = {-1e30f,-1e30f,-1e30f,-1e30f};
    float m2v[4] = {-1e30f,-1e30f,-1e30f,-1e30f};
    unsigned i1v[4] = {0,0,0,0};
#pragma unroll
    for (int mt = 0; mt < 5; ++mt) {
      const int code0 = w * 80 + mt * 16 + lq * 4;   // global code 0..639
      const int cg0 = code0 - g * NC;                // in-group code 0..319
      const float4 b2v = *(const float4*)(b2 + code0);
#pragma unroll
      for (int nt = 0; nt < 4; ++nt) {
        const int tokg = T0 + nt * 16 + l15;
        const float4 gv = *(const float4*)(gum + ((size_t)tokg * 2 + g) * NC + cg0);
        const f32x4 v = acc[mt][nt];
        const float ss[4] = {v[0] + b2v.x + gv.x, v[1] + b2v.y + gv.y,
                             v[2] + b2v.z + gv.z, v[3] + b2v.w + gv.w};
#pragma unroll
        for (int r = 0; r < 4; ++r) {
          const float sv = ss[r];
          const unsigned cc = (unsigned)(cg0 + r);
          if (sv > m1v[nt]) { m2v[nt] = m1v[nt]; m1v[nt] = sv; i1v[nt] = cc; }
          else if (sv > m2v[nt]) m2v[nt] = sv;
        }
      }
    }
#pragma unroll
    for (int mask = 16; mask <= 32; mask <<= 1) {
#pragma unroll
      for (int nt = 0; nt < 4; ++nt) {
        const float om1 = __shfl_xor(m1v[nt], mask);
        const float om2 = __shfl_xor(m2v[nt], mask);
        const unsigned oi = (unsigned)__shfl_xor((int)i1v[nt], mask);
        const bool take = (om1 > m1v[nt]) || (om1 == m1v[nt] && oi < i1v[nt]);
        if (take) { m2v[nt] = fmaxf(m1v[nt], om2); m1v[nt] = om1; i1v[nt] = oi; }
        else      { m2v[nt] = fmaxf(m2v[nt], om1); }
      }
    }
    if (l < 16) {
#pragma unroll
      for (int nt = 0; nt < 4; ++nt) {
        const int tok = nt * 16 + l15;
        redm1[w * 64 + tok] = m1v[nt];
        redm2[w * 64 + tok] = m2v[nt];
        redi [w * 64 + tok] = i1v[nt];
      }
    }
  }
  __syncthreads();

  // ---- final combine across the 4 waves of each group; flag near-ties
  if (tid < 128) {
    const int pg = tid >> 6;
    const int tok = tid & 63;
    float m1 = -1e30f, m2 = -1e30f; unsigned i1 = 0;
#pragma unroll
    for (int k = 0; k < 4; ++k) {
      const int ww = pg * 4 + k;   // ascending code blocks -> ties keep lower code
      const float a1 = redm1[ww * 64 + tok];
      const float a2 = redm2[ww * 64 + tok];
      const unsigned ai = redi[ww * 64 + tok];
      if (a1 > m1) { m2 = fmaxf(m1, a2); m1 = a1; i1 = ai; }
      else         { m2 = fmaxf(m2, a1); }
    }
    idxs[tid] = i1;
    if (m1 - m2 < MARGIN) {
      const unsigned pos = atomicAdd(cnt, 1u);
      if (pos < RCAP) list[pos] = (unsigned)(((T0 + tok) << 1) | pg);
    }
  }
  __syncthreads();

  // ---- gather emb rows -> out (128 pairs x 128 floats; 4 threads per pair)
#pragma unroll
  for (int i = 0; i < 8; ++i) {
    const int q = tid * 8 + i;     // float4 index, 0..4095
    const int p = q >> 5;          // pair 0..127
    const int dd = q & 31;
    const int pg = p >> 6;
    const int tok = p & 63;
    const unsigned idx = idxs[p];
    *(float4*)(out + (size_t)(T0 + tok) * OUTD + pg * VD + dd * 4)
      = *(const float4*)(emb + (size_t)idx * VD + dd * 4);
  }
}

// ---------------------------------------------------------------- refine, stage 1:
__global__ __launch_bounds__(512, 4)
void refine1_kernel(const float* __restrict__ x, const float* __restrict__ W1,
                    const float* __restrict__ b1,
                    const unsigned* __restrict__ cnt, const unsigned* __restrict__ list,
                    float* __restrict__ hdws) {
  __shared__ float xs[DIM];
  unsigned n = cnt[0]; if (n > RCAP) n = RCAP;
  const unsigned e = blockIdx.x;
  if (e >= n) return;
  const unsigned tok = list[e] >> 1;
  const int tid = threadIdx.x;                 // 512 == DIM
  xs[tid] = x[(size_t)tok * DIM + tid];
  __syncthreads();

  double a0 = 0.0, a1 = 0.0, c0 = 0.0, c1 = 0.0;
#pragma unroll 4
  for (int k = 0; k < DIM; k += 2) {
    const double x0 = (double)xs[k], x1 = (double)xs[k + 1];
    const float* r0 = W1 + (size_t)k * INNER + tid;
    const float* r1 = W1 + (size_t)(k + 1) * INNER + tid;
    a0 += x0 * (double)r0[0];
    a1 += x0 * (double)r0[512];
    c0 += x1 * (double)r1[0];
    c1 += x1 * (double)r1[512];
  }
  const double s0 = a0 + c0 + (double)b1[tid];
  const double s1 = a1 + c1 + (double)b1[tid + 512];
  hdws[(size_t)e * INNER + tid]       = (float)(0.5 * s0 * (1.0 + erf(s0 * 0.70710678118654752440)));
  hdws[(size_t)e * INNER + tid + 512] = (float)(0.5 * s1 * (1.0 + erf(s1 * 0.70710678118654752440)));
}

// ---------------------------------------------------------------- refine, stage 2:
__global__ __launch_bounds__(320, 4)
void refine2_kernel(const float* __restrict__ gum, const float* __restrict__ W2,
                    const float* __restrict__ b2, const float* __restrict__ emb,
                    float* __restrict__ out,
                    const unsigned* __restrict__ cnt, const unsigned* __restrict__ list,
                    const float* __restrict__ hdws) {
  __shared__ float hs[INNER];
  __shared__ double wv[5];
  __shared__ int wi[5];
  __shared__ int best;
  unsigned n = cnt[0]; if (n > RCAP) n = RCAP;
  const unsigned e = blockIdx.x;
  if (e >= n) return;
  const unsigned tok = list[e] >> 1;
  const int g = (int)(list[e] & 1u);
  const int tid = threadIdx.x;                 // 320 threads, one code each

  for (int j = tid; j < INNER; j += 320) hs[j] = hdws[(size_t)e * INNER + j];
  __syncthreads();

  const float* w2c = W2 + (size_t)g * NC + tid;   // column, stride 640 floats
  double acc = 0.0, accb = 0.0;
#pragma unroll 4
  for (int k = 0; k < INNER; k += 2) {
    acc  += (double)hs[k]     * (double)w2c[(size_t)k * (NC * NGRP)];
    accb += (double)hs[k + 1] * (double)w2c[(size_t)(k + 1) * (NC * NGRP)];
  }
  double v = acc + accb + (double)b2[g * NC + tid]
                        + (double)gum[((size_t)tok * 2 + g) * NC + tid];
  int bi = tid;
#pragma unroll
  for (int m = 1; m < 64; m <<= 1) {
    const double ov = __shfl_xor(v, m);
    const int oi = __shfl_xor(bi, m);
    if (ov > v || (ov == v && oi < bi)) { v = ov; bi = oi; }
  }
  if ((tid & 63) == 0) { wv[tid >> 6] = v; wi[tid >> 6] = bi; }
  __syncthreads();
  if (tid == 0) {
    double bv = wv[0]; int bb = wi[0];
#pragma unroll
    for (int k = 1; k < 5; ++k)
      if (wv[k] > bv || (wv[k] == bv && wi[k] < bb)) { bv = wv[k]; bb = wi[k]; }
    best = bb;
  }
  __syncthreads();
  if (tid < VD)
    out[(size_t)tok * OUTD + g * VD + tid] = emb[(size_t)best * VD + tid];
}

// ---------------------------------------------------------------- refine fallback
__global__ __launch_bounds__(512, 1)
void refine_kernel(const float* __restrict__ x, const float* __restrict__ gum,
                   const float* __restrict__ W1, const float* __restrict__ b1,
                   const float* __restrict__ W2, const float* __restrict__ b2,
                   const float* __restrict__ emb, float* __restrict__ out,
                   const unsigned* __restrict__ cnt, const unsigned* __restrict__ list) {
  __shared__ double xs[4][DIM];
  __shared__ double hd[4][INNER];
  __shared__ double sc[4][NC];
  __shared__ int amax[4];
  const int tid = threadIdx.x;
  unsigned n = cnt[0];
  if (n > RCAP) n = RCAP;

  for (unsigned base = blockIdx.x * 4u; base < n; base += gridDim.x * 4u) {
    const int nb = (int)((n - base) < 4u ? (n - base) : 4u);
    unsigned ng[4];
#pragma unroll
    for (int e = 0; e < 4; ++e) ng[e] = list[base + (e < nb ? e : 0)];

    for (int e = 0; e < nb; ++e)
      xs[e][tid] = (double)x[(size_t)(ng[e] >> 1) * DIM + tid];
    __syncthreads();

#pragma unroll
    for (int jj = 0; jj < 2; ++jj) {
      const int j = tid + jj * 512;
      double a0 = 0, a1 = 0, a2 = 0, a3 = 0;
      for (int k = 0; k < DIM; ++k) {
        const double wvv = (double)W1[(size_t)k * INNER + j];
        a0 += xs[0][k] * wvv; a1 += xs[1][k] * wvv;
        a2 += xs[2][k] * wvv; a3 += xs[3][k] * wvv;
      }
      const double bb = (double)b1[j];
      const double s0 = a0 + bb, s1 = a1 + bb, s2 = a2 + bb, s3 = a3 + bb;
      hd[0][j] = 0.5 * s0 * (1.0 + erf(s0 * 0.70710678118654752440));
      hd[1][j] = 0.5 * s1 * (1.0 + erf(s1 * 0.70710678118654752440));
      hd[2][j] = 0.5 * s2 * (1.0 + erf(s2 * 0.70710678118654752440));
      hd[3][j] = 0.5 * s3 * (1.0 + erf(s3 * 0.70710678118654752440));
    }
    __syncthreads();

    for (int task = tid; task < 4 * NC; task += 512) {
      const int e = task / NC;
      const int c = task - e * NC;
      if (e < nb) {
        const unsigned tok = ng[e] >> 1;
        const int gg = (int)(ng[e] & 1u);
        const float* w2c = W2 + (size_t)gg * NC + c;
        double acc = 0.0;
        for (int k = 0; k < INNER; ++k)
          acc += hd[e][k] * (double)w2c[(size_t)k * (NC * NGRP)];
        sc[e][c] = acc + (double)b2[gg * NC + c]
                       + (double)gum[((size_t)tok * 2 + gg) * NC + c];
      }
    }
    __syncthreads();

    if (tid < 4 && tid < nb) {
      double bestv = sc[tid][0]; int bi = 0;
      for (int c = 1; c < NC; ++c)
        if (sc[tid][c] > bestv) { bestv = sc[tid][c]; bi = c; }
      amax[tid] = bi;
    }
    __syncthreads();

    {
      const int e = tid >> 7;
      const int d = tid & 127;
      if (e < nb) {
        const unsigned tok = ng[e] >> 1;
        const int gg = (int)(ng[e] & 1u);
        out[(size_t)tok * OUTD + gg * VD + d] = emb[(size_t)amax[e] * VD + d];
      }
    }
    __syncthreads();
  }
}

// ---------------------------------------------------------------- launch
extern "C" void kernel_launch(void* const* d_in, const int* in_sizes, int n_in,
                              void* d_out, int out_size, void* d_ws, size_t ws_size,
                              hipStream_t stream) {
  (void)in_sizes; (void)n_in; (void)out_size;
  const float* x   = (const float*)d_in[0];
  const float* gum = (const float*)d_in[1];
  const float* W1  = (const float*)d_in[2];
  const float* b1  = (const float*)d_in[3];
  const float* W2  = (const float*)d_in[4];
  const float* b2  = (const float*)d_in[5];
  const float* emb = (const float*)d_in[6];
  float* out = (float*)d_out;
  char* ws = (char*)d_ws;
  unsigned* cnt  = (unsigned*)ws;
  unsigned* list = (unsigned*)(ws + 16);
  _Float16* W1T = (_Float16*)(ws + W1T_OFF);
  _Float16* W2T = (_Float16*)(ws + W2T_OFF);
  float* hdws = (float*)(ws + HD_OFF);

  hipFuncSetAttribute((const void*)fused_kernel,
                      hipFuncAttributeMaxDynamicSharedMemorySize, SMEM_BYTES);

  prep_kernel<<<INNER + NC * NGRP, 256, 0, stream>>>(W1, W2, W1T, W2T, cnt);
  fused_kernel<<<NTOK / 64, 512, SMEM_BYTES, stream>>>(x, gum, W1T, W2T, b1, b2,
                                                       emb, out, cnt, list);
  const bool big_ws = ws_size >= (size_t)HD_OFF + (size_t)RCAP * INNER * sizeof(float);
  if (big_ws) {
    refine1_kernel<<<RCAP, 512, 0, stream>>>(x, W1, b1, cnt, list, hdws);
    refine2_kernel<<<RCAP, 320, 0, stream>>>(gum, W2, b2, emb, out, cnt, list, hdws);
  } else {
    refine_kernel<<<256, 512, 0, stream>>>(x, gum, W1, b1, W2, b2, emb, out, cnt, list);
  }
}

// Round 4
// 331.917 us; speedup vs baseline: 1.2518x; 1.2518x over previous
//
#include <hip/hip_runtime.h>
#include <math.h>

// GumbelQuantizer: out[n,g,:] = emb[argmax_c(logits[n,g,c] + gumbels[n,g,c])]
// (straight-through forward == hard one-hot; softmax/TAU are argmax-invariant).
// fp16-MFMA fast path + margin-flagged fp64 exact refine for near-ties.
// R4: fragment-major weight packing — every MFMA A-frag load is one contiguous
// 1KB wave transaction (R2/R3 had 16-way-scattered 64B reads; latency-bound at
// MfmaUtil 8%). K-loop bodies reverted to the simpler R2 form (R3 prefetch hurt).

#define NTOK   32768   // BS*L
#define DIM    512
#define INNER  1024
#define NC     320
#define NGRP   2
#define VD     128
#define OUTD   256
#define RCAP   2048            // refine list capacity (expected ~520 flagged)
#define W1F_OFF (1u<<20)       // ws byte offsets: W1F 1MB at [1MB,2MB)
#define W2F_OFF (1u<<21)       // W2F 1.25MB at [2MB,3.25MB)
#define HD_OFF  (1u<<22)       // fp32 h rows for flagged entries (RCAP*4KB = 8MB)
#define MARGIN 8.0e-3f         // ~4x estimated max fp16-path logit error
#define SMEM_BYTES (131072 + 6144 + 512)

typedef _Float16 half8 __attribute__((ext_vector_type(8)));
typedef _Float16 half4 __attribute__((ext_vector_type(4)));
typedef float    f32x4 __attribute__((ext_vector_type(4)));

// ---------------------------------------------------------------- prep:
// Pack weights fragment-major for the fused kernel's MFMA A-loads:
//   W1F[((ks*64 + ib)*64 + l)*8 + j] = W1[ks*32 + (l>>4)*8 + j][ib*16 + (l&15)]
//   (ks: k-step 0..15, ib: 16-row inner block 0..63, l: lane 0..63, j: 0..7)
//   W2F[((ks*40 + cb)*64 + l)*8 + j] = W2[ks*32 + (l>>4)*8 + j][cb*16 + (l&15)]
//   (ks 0..31, cb 0..39)
// One half8 per thread; writes are linear, reads strided (weights tiny).
#define W1F_N (16 * 64 * 64)   // 65536 half8
#define W2F_N (32 * 40 * 64)   // 81920 half8
__global__ void prep_kernel(const float* __restrict__ W1, const float* __restrict__ W2,
                            _Float16* __restrict__ W1F, _Float16* __restrict__ W2F,
                            unsigned* __restrict__ cnt) {
  const int o = blockIdx.x * 256 + threadIdx.x;
  if (o == 0) cnt[0] = 0u;
  if (o < W1F_N) {
    const int l = o & 63, ib = (o >> 6) & 63, ks = o >> 12;
    const int inner = ib * 16 + (l & 15);
    const int kb = ks * 32 + (l >> 4) * 8;
    _Float16* d = W1F + (size_t)o * 8;
#pragma unroll
    for (int j = 0; j < 8; ++j)
      d[j] = (_Float16)W1[(size_t)(kb + j) * INNER + inner];
  } else {
    const int o2 = o - W1F_N;
    if (o2 < W2F_N) {
      const int l = o2 & 63, cb = (o2 >> 6) % 40, ks = o2 / (40 * 64);
      const int code = cb * 16 + (l & 15);
      const int kb = ks * 32 + (l >> 4) * 8;
      _Float16* d = W2F + (size_t)o2 * 8;
#pragma unroll
      for (int j = 0; j < 8; ++j)
        d[j] = (_Float16)W2[(size_t)(kb + j) * (NC * NGRP) + code];
    }
  }
}

__device__ __forceinline__ float gelu_f(float s) {
  return 0.5f * s * (1.0f + erff(s * 0.70710678118654752440f));
}

// ---------------------------------------------------------------- fused:
// one block = 64 tokens, 8 waves (512 thr).
// LDS: [0,64K)   x tile fp16 [64][512], row-swizzled (phase 1 B operand)
//      [0,128K)  h tile fp16 [64][1024], row-swizzled (overwrites x after GEMM1)
//      [128K..)  reduction scratch + idx
__global__ __launch_bounds__(512, 2)
void fused_kernel(const float* __restrict__ x, const float* __restrict__ gum,
                  const _Float16* __restrict__ W1F, const _Float16* __restrict__ W2F,
                  const float* __restrict__ b1, const float* __restrict__ b2,
                  const float* __restrict__ emb, float* __restrict__ out,
                  unsigned* __restrict__ cnt, unsigned* __restrict__ list) {
  extern __shared__ char smem[];
  float*    redm1 = (float*)(smem + 131072);
  float*    redm2 = (float*)(smem + 131072 + 2048);
  unsigned* redi  = (unsigned*)(smem + 131072 + 4096);
  unsigned* idxs  = (unsigned*)(smem + 131072 + 6144);

  const int tid = threadIdx.x;
  const int w   = tid >> 6;
  const int l   = tid & 63;
  const int l15 = l & 15;
  const int lq  = l >> 4;
  const int T0  = blockIdx.x << 6;

  // ---- stage x (64 x 512 fp32 -> fp16, swizzled, row stride 1024B)
#pragma unroll
  for (int i = 0; i < 16; ++i) {
    const int q = tid + i * 512;          // 0..8191 float4 slots
    const int row = q >> 7;
    const int c = (q & 127) << 2;
    const float4 v = *(const float4*)(x + (size_t)(T0 + row) * DIM + c);
    half4 hv; hv[0] = (_Float16)v.x; hv[1] = (_Float16)v.y;
    hv[2] = (_Float16)v.z; hv[3] = (_Float16)v.w;
    const unsigned byte = ((unsigned)(row * 1024 + c * 2)) ^ ((unsigned)(row & 7) << 4);
    *(half4*)(smem + byte) = hv;
  }
  __syncthreads();

  // ---- Phase 1: h = gelu(x @ W1 + b1). Wave w owns inner slice [w*128, w*128+128).
  {
    f32x4 acc[8][4];
#pragma unroll
    for (int i = 0; i < 8; ++i)
#pragma unroll
      for (int j = 0; j < 4; ++j) { f32x4 z = {0.f,0.f,0.f,0.f}; acc[i][j] = z; }

    // fragment-major: a[mt] for (ks) = w1f + (ks*64 + mt)*512, lane-consecutive 16B
    const _Float16* w1f = W1F + (size_t)(w * 8) * 512 + (size_t)l * 8;
    for (int ks = 0; ks < 16; ++ks) {
      const int k0 = ks * 32;
      half8 a[8], bf[4];
#pragma unroll
      for (int mt = 0; mt < 8; ++mt)
        a[mt] = *(const half8*)(w1f + (size_t)(ks * 64 + mt) * 512);
#pragma unroll
      for (int nt = 0; nt < 4; ++nt) {
        const int token = nt * 16 + l15;
        const unsigned byte = ((unsigned)(token * 1024 + (k0 + lq * 8) * 2))
                              ^ ((unsigned)(token & 7) << 4);
        bf[nt] = *(const half8*)(smem + byte);
      }
#pragma unroll
      for (int mt = 0; mt < 8; ++mt)
#pragma unroll
        for (int nt = 0; nt < 4; ++nt)
          acc[mt][nt] = __builtin_amdgcn_mfma_f32_16x16x32_f16(a[mt], bf[nt], acc[mt][nt], 0, 0, 0);
    }
    __syncthreads();  // all waves done reading x tile

    // epilogue: +b1, exact-erf GELU, fp16 -> h LDS [64][1024], row-swizzled (2048B rows)
#pragma unroll
    for (int mt = 0; mt < 8; ++mt) {
      const int inner0 = w * 128 + mt * 16 + lq * 4;
      const float4 bv = *(const float4*)(b1 + inner0);
#pragma unroll
      for (int nt = 0; nt < 4; ++nt) {
        const int token = nt * 16 + l15;
        const f32x4 v = acc[mt][nt];
        half4 hv;
        hv[0] = (_Float16)gelu_f(v[0] + bv.x);
        hv[1] = (_Float16)gelu_f(v[1] + bv.y);
        hv[2] = (_Float16)gelu_f(v[2] + bv.z);
        hv[3] = (_Float16)gelu_f(v[3] + bv.w);
        const unsigned byte = ((unsigned)(token * 2048 + inner0 * 2))
                              ^ ((unsigned)(token & 7) << 4);
        *(half4*)(smem + byte) = hv;
      }
    }
  }
  __syncthreads();

  // ---- Phase 2: logits = h @ W2 + b2 + gumbels; top-2 per (token,group).
  const int g = w >> 2;
  {
    f32x4 acc[5][4];
#pragma unroll
    for (int i = 0; i < 5; ++i)
#pragma unroll
      for (int j = 0; j < 4; ++j) { f32x4 z = {0.f,0.f,0.f,0.f}; acc[i][j] = z; }

    const _Float16* w2f = W2F + (size_t)(w * 5) * 512 + (size_t)l * 8;
    for (int ks = 0; ks < 32; ++ks) {
      const int k0 = ks * 32;
      half8 a[5], bf[4];
#pragma unroll
      for (int mt = 0; mt < 5; ++mt)
        a[mt] = *(const half8*)(w2f + (size_t)(ks * 40 + mt) * 512);
#pragma unroll
      for (int nt = 0; nt < 4; ++nt) {
        const int token = nt * 16 + l15;
        const unsigned byte = ((unsigned)(token * 2048 + (k0 + lq * 8) * 2))
                              ^ ((unsigned)(token & 7) << 4);
        bf[nt] = *(const half8*)(smem + byte);
      }
#pragma unroll
      for (int mt = 0; mt < 5; ++mt)
#pragma unroll
        for (int nt = 0; nt < 4; ++nt)
          acc[mt][nt] = __builtin_amdgcn_mfma_f32_16x16x32_f16(a[mt], bf[nt], acc[mt][nt], 0, 0, 0);
    }

    // per-lane top-2 (ascending code order -> first-index tie-break like np.argmax)
    float m1v[4] = {-1e30f,-1e30f,-1e30f,-1e30f};
    float m2v[4] = {-1e30f,-1e30f,-1e30f,-1e30f};
    unsigned i1v[4] = {0,0,0,0};
#pragma unroll
    for (int mt = 0; mt < 5; ++mt) {
      const int code0 = w * 80 + mt * 16 + lq * 4;   // global code 0..639
      const int cg0 = code0 - g * NC;                // in-group code 0..319
      const float4 b2v = *(const float4*)(b2 + code0);
#pragma unroll
      for (int nt = 0; nt < 4; ++nt) {
        const int tokg = T0 + nt * 16 + l15;
        const float4 gv = *(const float4*)(gum + ((size_t)tokg * 2 + g) * NC + cg0);
        const f32x4 v = acc[mt][nt];
        const float ss[4] = {v[0] + b2v.x + gv.x, v[1] + b2v.y + gv.y,
                             v[2] + b2v.z + gv.z, v[3] + b2v.w + gv.w};
#pragma unroll
        for (int r = 0; r < 4; ++r) {
          const float sv = ss[r];
          const unsigned cc = (unsigned)(cg0 + r);
          if (sv > m1v[nt]) { m2v[nt] = m1v[nt]; m1v[nt] = sv; i1v[nt] = cc; }
          else if (sv > m2v[nt]) m2v[nt] = sv;
        }
      }
    }
#pragma unroll
    for (int mask = 16; mask <= 32; mask <<= 1) {
#pragma unroll
      for (int nt = 0; nt < 4; ++nt) {
        const float om1 = __shfl_xor(m1v[nt], mask);
        const float om2 = __shfl_xor(m2v[nt], mask);
        const unsigned oi = (unsigned)__shfl_xor((int)i1v[nt], mask);
        const bool take = (om1 > m1v[nt]) || (om1 == m1v[nt] && oi < i1v[nt]);
        if (take) { m2v[nt] = fmaxf(m1v[nt], om2); m1v[nt] = om1; i1v[nt] = oi; }
        else      { m2v[nt] = fmaxf(m2v[nt], om1); }
      }
    }
    if (l < 16) {
#pragma unroll
      for (int nt = 0; nt < 4; ++nt) {
        const int tok = nt * 16 + l15;
        redm1[w * 64 + tok] = m1v[nt];
        redm2[w * 64 + tok] = m2v[nt];
        redi [w * 64 + tok] = i1v[nt];
      }
    }
  }
  __syncthreads();

  // ---- final combine across the 4 waves of each group; flag near-ties
  if (tid < 128) {
    const int pg = tid >> 6;
    const int tok = tid & 63;
    float m1 = -1e30f, m2 = -1e30f; unsigned i1 = 0;
#pragma unroll
    for (int k = 0; k < 4; ++k) {
      const int ww = pg * 4 + k;   // ascending code blocks -> ties keep lower code
      const float a1 = redm1[ww * 64 + tok];
      const float a2 = redm2[ww * 64 + tok];
      const unsigned ai = redi[ww * 64 + tok];
      if (a1 > m1) { m2 = fmaxf(m1, a2); m1 = a1; i1 = ai; }
      else         { m2 = fmaxf(m2, a1); }
    }
    idxs[tid] = i1;
    if (m1 - m2 < MARGIN) {
      const unsigned pos = atomicAdd(cnt, 1u);
      if (pos < RCAP) list[pos] = (unsigned)(((T0 + tok) << 1) | pg);
    }
  }
  __syncthreads();

  // ---- gather emb rows -> out (128 pairs x 128 floats; 4 threads per pair)
#pragma unroll
  for (int i = 0; i < 8; ++i) {
    const int q = tid * 8 + i;     // float4 index, 0..4095
    const int p = q >> 5;          // pair 0..127
    const int dd = q & 31;
    const int pg = p >> 6;
    const int tok = p & 63;
    const unsigned idx = idxs[p];
    *(float4*)(out + (size_t)(T0 + tok) * OUTD + pg * VD + dd * 4)
      = *(const float4*)(emb + (size_t)idx * VD + dd * 4);
  }
}

// ---------------------------------------------------------------- refine, stage 1:
__global__ __launch_bounds__(512, 4)
void refine1_kernel(const float* __restrict__ x, const float* __restrict__ W1,
                    const float* __restrict__ b1,
                    const unsigned* __restrict__ cnt, const unsigned* __restrict__ list,
                    float* __restrict__ hdws) {
  __shared__ float xs[DIM];
  unsigned n = cnt[0]; if (n > RCAP) n = RCAP;
  const unsigned e = blockIdx.x;
  if (e >= n) return;
  const unsigned tok = list[e] >> 1;
  const int tid = threadIdx.x;                 // 512 == DIM
  xs[tid] = x[(size_t)tok * DIM + tid];
  __syncthreads();

  double a0 = 0.0, a1 = 0.0, c0 = 0.0, c1 = 0.0;
#pragma unroll 4
  for (int k = 0; k < DIM; k += 2) {
    const double x0 = (double)xs[k], x1 = (double)xs[k + 1];
    const float* r0 = W1 + (size_t)k * INNER + tid;
    const float* r1 = W1 + (size_t)(k + 1) * INNER + tid;
    a0 += x0 * (double)r0[0];
    a1 += x0 * (double)r0[512];
    c0 += x1 * (double)r1[0];
    c1 += x1 * (double)r1[512];
  }
  const double s0 = a0 + c0 + (double)b1[tid];
  const double s1 = a1 + c1 + (double)b1[tid + 512];
  hdws[(size_t)e * INNER + tid]       = (float)(0.5 * s0 * (1.0 + erf(s0 * 0.70710678118654752440)));
  hdws[(size_t)e * INNER + tid + 512] = (float)(0.5 * s1 * (1.0 + erf(s1 * 0.70710678118654752440)));
}

// ---------------------------------------------------------------- refine, stage 2:
__global__ __launch_bounds__(320, 4)
void refine2_kernel(const float* __restrict__ gum, const float* __restrict__ W2,
                    const float* __restrict__ b2, const float* __restrict__ emb,
                    float* __restrict__ out,
                    const unsigned* __restrict__ cnt, const unsigned* __restrict__ list,
                    const float* __restrict__ hdws) {
  __shared__ float hs[INNER];
  __shared__ double wv[5];
  __shared__ int wi[5];
  __shared__ int best;
  unsigned n = cnt[0]; if (n > RCAP) n = RCAP;
  const unsigned e = blockIdx.x;
  if (e >= n) return;
  const unsigned tok = list[e] >> 1;
  const int g = (int)(list[e] & 1u);
  const int tid = threadIdx.x;                 // 320 threads, one code each

  for (int j = tid; j < INNER; j += 320) hs[j] = hdws[(size_t)e * INNER + j];
  __syncthreads();

  const float* w2c = W2 + (size_t)g * NC + tid;   // column, stride 640 floats
  double acc = 0.0, accb = 0.0;
#pragma unroll 4
  for (int k = 0; k < INNER; k += 2) {
    acc  += (double)hs[k]     * (double)w2c[(size_t)k * (NC * NGRP)];
    accb += (double)hs[k + 1] * (double)w2c[(size_t)(k + 1) * (NC * NGRP)];
  }
  double v = acc + accb + (double)b2[g * NC + tid]
                        + (double)gum[((size_t)tok * 2 + g) * NC + tid];
  int bi = tid;
#pragma unroll
  for (int m = 1; m < 64; m <<= 1) {
    const double ov = __shfl_xor(v, m);
    const int oi = __shfl_xor(bi, m);
    if (ov > v || (ov == v && oi < bi)) { v = ov; bi = oi; }
  }
  if ((tid & 63) == 0) { wv[tid >> 6] = v; wi[tid >> 6] = bi; }
  __syncthreads();
  if (tid == 0) {
    double bv = wv[0]; int bb = wi[0];
#pragma unroll
    for (int k = 1; k < 5; ++k)
      if (wv[k] > bv || (wv[k] == bv && wi[k] < bb)) { bv = wv[k]; bb = wi[k]; }
    best = bb;
  }
  __syncthreads();
  if (tid < VD)
    out[(size_t)tok * OUTD + g * VD + tid] = emb[(size_t)best * VD + tid];
}

// ---------------------------------------------------------------- refine fallback
__global__ __launch_bounds__(512, 1)
void refine_kernel(const float* __restrict__ x, const float* __restrict__ gum,
                   const float* __restrict__ W1, const float* __restrict__ b1,
                   const float* __restrict__ W2, const float* __restrict__ b2,
                   const float* __restrict__ emb, float* __restrict__ out,
                   const unsigned* __restrict__ cnt, const unsigned* __restrict__ list) {
  __shared__ double xs[4][DIM];
  __shared__ double hd[4][INNER];
  __shared__ double sc[4][NC];
  __shared__ int amax[4];
  const int tid = threadIdx.x;
  unsigned n = cnt[0];
  if (n > RCAP) n = RCAP;

  for (unsigned base = blockIdx.x * 4u; base < n; base += gridDim.x * 4u) {
    const int nb = (int)((n - base) < 4u ? (n - base) : 4u);
    unsigned ng[4];
#pragma unroll
    for (int e = 0; e < 4; ++e) ng[e] = list[base + (e < nb ? e : 0)];

    for (int e = 0; e < nb; ++e)
      xs[e][tid] = (double)x[(size_t)(ng[e] >> 1) * DIM + tid];
    __syncthreads();

#pragma unroll
    for (int jj = 0; jj < 2; ++jj) {
      const int j = tid + jj * 512;
      double a0 = 0, a1 = 0, a2 = 0, a3 = 0;
      for (int k = 0; k < DIM; ++k) {
        const double wvv = (double)W1[(size_t)k * INNER + j];
        a0 += xs[0][k] * wvv; a1 += xs[1][k] * wvv;
        a2 += xs[2][k] * wvv; a3 += xs[3][k] * wvv;
      }
      const double bb = (double)b1[j];
      const double s0 = a0 + bb, s1 = a1 + bb, s2 = a2 + bb, s3 = a3 + bb;
      hd[0][j] = 0.5 * s0 * (1.0 + erf(s0 * 0.70710678118654752440));
      hd[1][j] = 0.5 * s1 * (1.0 + erf(s1 * 0.70710678118654752440));
      hd[2][j] = 0.5 * s2 * (1.0 + erf(s2 * 0.70710678118654752440));
      hd[3][j] = 0.5 * s3 * (1.0 + erf(s3 * 0.70710678118654752440));
    }
    __syncthreads();

    for (int task = tid; task < 4 * NC; task += 512) {
      const int e = task / NC;
      const int c = task - e * NC;
      if (e < nb) {
        const unsigned tok = ng[e] >> 1;
        const int gg = (int)(ng[e] & 1u);
        const float* w2c = W2 + (size_t)gg * NC + c;
        double acc = 0.0;
        for (int k = 0; k < INNER; ++k)
          acc += hd[e][k] * (double)w2c[(size_t)k * (NC * NGRP)];
        sc[e][c] = acc + (double)b2[gg * NC + c]
                       + (double)gum[((size_t)tok * 2 + gg) * NC + c];
      }
    }
    __syncthreads();

    if (tid < 4 && tid < nb) {
      double bestv = sc[tid][0]; int bi = 0;
      for (int c = 1; c < NC; ++c)
        if (sc[tid][c] > bestv) { bestv = sc[tid][c]; bi = c; }
      amax[tid] = bi;
    }
    __syncthreads();

    {
      const int e = tid >> 7;
      const int d = tid & 127;
      if (e < nb) {
        const unsigned tok = ng[e] >> 1;
        const int gg = (int)(ng[e] & 1u);
        out[(size_t)tok * OUTD + gg * VD + d] = emb[(size_t)amax[e] * VD + d];
      }
    }
    __syncthreads();
  }
}

// ---------------------------------------------------------------- launch
extern "C" void kernel_launch(void* const* d_in, const int* in_sizes, int n_in,
                              void* d_out, int out_size, void* d_ws, size_t ws_size,
                              hipStream_t stream) {
  (void)in_sizes; (void)n_in; (void)out_size;
  const float* x   = (const float*)d_in[0];
  const float* gum = (const float*)d_in[1];
  const float* W1  = (const float*)d_in[2];
  const float* b1  = (const float*)d_in[3];
  const float* W2  = (const float*)d_in[4];
  const float* b2  = (const float*)d_in[5];
  const float* emb = (const float*)d_in[6];
  float* out = (float*)d_out;
  char* ws = (char*)d_ws;
  unsigned* cnt  = (unsigned*)ws;
  unsigned* list = (unsigned*)(ws + 16);
  _Float16* W1F = (_Float16*)(ws + W1F_OFF);
  _Float16* W2F = (_Float16*)(ws + W2F_OFF);
  float* hdws = (float*)(ws + HD_OFF);

  hipFuncSetAttribute((const void*)fused_kernel,
                      hipFuncAttributeMaxDynamicSharedMemorySize, SMEM_BYTES);

  const int prep_items = W1F_N + W2F_N;                 // 147456 half8's
  prep_kernel<<<(prep_items + 255) / 256, 256, 0, stream>>>(W1, W2, W1F, W2F, cnt);
  fused_kernel<<<NTOK / 64, 512, SMEM_BYTES, stream>>>(x, gum, W1F, W2F, b1, b2,
                                                       emb, out, cnt, list);
  const bool big_ws = ws_size >= (size_t)HD_OFF + (size_t)RCAP * INNER * sizeof(float);
  if (big_ws) {
    refine1_kernel<<<RCAP, 512, 0, stream>>>(x, W1, b1, cnt, list, hdws);
    refine2_kernel<<<RCAP, 320, 0, stream>>>(gum, W2, b2, emb, out, cnt, list, hdws);
  } else {
    refine_kernel<<<256, 512, 0, stream>>>(x, gum, W1, b1, W2, b2, emb, out, cnt, list);
  }
}

// Round 5
// 269.160 us; speedup vs baseline: 1.5436x; 1.2332x over previous
//
#include <hip/hip_runtime.h>
#include <math.h>

// GumbelQuantizer: out[n,g,:] = emb[argmax_c(logits[n,g,c] + gumbels[n,g,c])]
// (straight-through forward == hard one-hot; softmax/TAU are argmax-invariant).
// fp16-MFMA fast path + margin-flagged fp64 exact refine for near-ties.
// R5: 32-token tile -> LDS 69KB -> 2 blocks/CU (was 1; Occupancy 23.7%,
// MfmaUtil pinned at 9% across 3 load-arrangement variants => latency-bound
// at 2 waves/SIMD with barrier-serialized phases, not load-pattern-bound).

#define NTOK   32768   // BS*L
#define DIM    512
#define INNER  1024
#define NC     320
#define NGRP   2
#define VD     128
#define OUTD   256
#define RCAP   2048            // refine list capacity (expected ~520 flagged)
#define W1F_OFF (1u<<20)       // ws byte offsets: W1F 1MB at [1MB,2MB)
#define W2F_OFF (1u<<21)       // W2F 1.25MB at [2MB,3.25MB)
#define HD_OFF  (1u<<22)       // fp32 h rows for flagged entries (RCAP*4KB = 8MB)
#define MARGIN 8.0e-3f         // ~4x estimated max fp16-path logit error
#define SMEM_BYTES (65536 + 3328)

typedef _Float16 half8 __attribute__((ext_vector_type(8)));
typedef _Float16 half4 __attribute__((ext_vector_type(4)));
typedef float    f32x4 __attribute__((ext_vector_type(4)));

// ---------------------------------------------------------------- prep:
// Pack weights fragment-major for the fused kernel's MFMA A-loads:
//   W1F[((ks*64 + ib)*64 + l)*8 + j] = W1[ks*32 + (l>>4)*8 + j][ib*16 + (l&15)]
//   W2F[((ks*40 + cb)*64 + l)*8 + j] = W2[ks*32 + (l>>4)*8 + j][cb*16 + (l&15)]
#define W1F_N (16 * 64 * 64)   // 65536 half8
#define W2F_N (32 * 40 * 64)   // 81920 half8
__global__ void prep_kernel(const float* __restrict__ W1, const float* __restrict__ W2,
                            _Float16* __restrict__ W1F, _Float16* __restrict__ W2F,
                            unsigned* __restrict__ cnt) {
  const int o = blockIdx.x * 256 + threadIdx.x;
  if (o == 0) cnt[0] = 0u;
  if (o < W1F_N) {
    const int l = o & 63, ib = (o >> 6) & 63, ks = o >> 12;
    const int inner = ib * 16 + (l & 15);
    const int kb = ks * 32 + (l >> 4) * 8;
    _Float16* d = W1F + (size_t)o * 8;
#pragma unroll
    for (int j = 0; j < 8; ++j)
      d[j] = (_Float16)W1[(size_t)(kb + j) * INNER + inner];
  } else {
    const int o2 = o - W1F_N;
    if (o2 < W2F_N) {
      const int l = o2 & 63, cb = (o2 >> 6) % 40, ks = o2 / (40 * 64);
      const int code = cb * 16 + (l & 15);
      const int kb = ks * 32 + (l >> 4) * 8;
      _Float16* d = W2F + (size_t)o2 * 8;
#pragma unroll
      for (int j = 0; j < 8; ++j)
        d[j] = (_Float16)W2[(size_t)(kb + j) * (NC * NGRP) + code];
    }
  }
}

__device__ __forceinline__ float gelu_f(float s) {
  return 0.5f * s * (1.0f + erff(s * 0.70710678118654752440f));
}

// ---------------------------------------------------------------- fused:
// one block = 32 tokens, 8 waves (512 thr); 2 blocks/CU.
// LDS: [0,32K)  x tile fp16 [32][512], row-swizzled (phase 1 B operand)
//      [0,64K)  h tile fp16 [32][1024], row-swizzled (overwrites x after GEMM1)
//      [64K..)  reduction scratch + idx
__global__ __launch_bounds__(512, 4)
void fused_kernel(const float* __restrict__ x, const float* __restrict__ gum,
                  const _Float16* __restrict__ W1F, const _Float16* __restrict__ W2F,
                  const float* __restrict__ b1, const float* __restrict__ b2,
                  const float* __restrict__ emb, float* __restrict__ out,
                  unsigned* __restrict__ cnt, unsigned* __restrict__ list) {
  extern __shared__ char smem[];
  float*    redm1 = (float*)(smem + 65536);
  float*    redm2 = (float*)(smem + 65536 + 1024);
  unsigned* redi  = (unsigned*)(smem + 65536 + 2048);
  unsigned* idxs  = (unsigned*)(smem + 65536 + 3072);

  const int tid = threadIdx.x;
  const int w   = tid >> 6;
  const int l   = tid & 63;
  const int l15 = l & 15;
  const int lq  = l >> 4;
  const int T0  = blockIdx.x << 5;

  // ---- stage x (32 x 512 fp32 -> fp16, swizzled, row stride 1024B)
#pragma unroll
  for (int i = 0; i < 8; ++i) {
    const int q = tid + i * 512;          // 0..4095 float4 slots
    const int row = q >> 7;
    const int c = (q & 127) << 2;
    const float4 v = *(const float4*)(x + (size_t)(T0 + row) * DIM + c);
    half4 hv; hv[0] = (_Float16)v.x; hv[1] = (_Float16)v.y;
    hv[2] = (_Float16)v.z; hv[3] = (_Float16)v.w;
    const unsigned byte = ((unsigned)(row * 1024 + c * 2)) ^ ((unsigned)(row & 7) << 4);
    *(half4*)(smem + byte) = hv;
  }
  __syncthreads();

  // ---- Phase 1: h = gelu(x @ W1 + b1). Wave w owns inner slice [w*128, w*128+128).
  {
    f32x4 acc[8][2];
#pragma unroll
    for (int i = 0; i < 8; ++i)
#pragma unroll
      for (int j = 0; j < 2; ++j) { f32x4 z = {0.f,0.f,0.f,0.f}; acc[i][j] = z; }

    // fragment-major: a[mt] for (ks) = w1f + (ks*64 + mt)*512, lane-consecutive 16B
    const _Float16* w1f = W1F + (size_t)(w * 8) * 512 + (size_t)l * 8;
    for (int ks = 0; ks < 16; ++ks) {
      const int k0 = ks * 32;
      half8 a[8], bf[2];
#pragma unroll
      for (int mt = 0; mt < 8; ++mt)
        a[mt] = *(const half8*)(w1f + (size_t)(ks * 64 + mt) * 512);
#pragma unroll
      for (int nt = 0; nt < 2; ++nt) {
        const int token = nt * 16 + l15;
        const unsigned byte = ((unsigned)(token * 1024 + (k0 + lq * 8) * 2))
                              ^ ((unsigned)(token & 7) << 4);
        bf[nt] = *(const half8*)(smem + byte);
      }
#pragma unroll
      for (int mt = 0; mt < 8; ++mt)
#pragma unroll
        for (int nt = 0; nt < 2; ++nt)
          acc[mt][nt] = __builtin_amdgcn_mfma_f32_16x16x32_f16(a[mt], bf[nt], acc[mt][nt], 0, 0, 0);
    }
    __syncthreads();  // all waves done reading x tile

    // epilogue: +b1, exact-erf GELU, fp16 -> h LDS [32][1024], row-swizzled (2048B rows)
#pragma unroll
    for (int mt = 0; mt < 8; ++mt) {
      const int inner0 = w * 128 + mt * 16 + lq * 4;
      const float4 bv = *(const float4*)(b1 + inner0);
#pragma unroll
      for (int nt = 0; nt < 2; ++nt) {
        const int token = nt * 16 + l15;
        const f32x4 v = acc[mt][nt];
        half4 hv;
        hv[0] = (_Float16)gelu_f(v[0] + bv.x);
        hv[1] = (_Float16)gelu_f(v[1] + bv.y);
        hv[2] = (_Float16)gelu_f(v[2] + bv.z);
        hv[3] = (_Float16)gelu_f(v[3] + bv.w);
        const unsigned byte = ((unsigned)(token * 2048 + inner0 * 2))
                              ^ ((unsigned)(token & 7) << 4);
        *(half4*)(smem + byte) = hv;
      }
    }
  }
  __syncthreads();

  // ---- Phase 2: logits = h @ W2 + b2 + gumbels; top-2 per (token,group).
  const int g = w >> 2;
  {
    f32x4 acc[5][2];
#pragma unroll
    for (int i = 0; i < 5; ++i)
#pragma unroll
      for (int j = 0; j < 2; ++j) { f32x4 z = {0.f,0.f,0.f,0.f}; acc[i][j] = z; }

    const _Float16* w2f = W2F + (size_t)(w * 5) * 512 + (size_t)l * 8;
    for (int ks = 0; ks < 32; ++ks) {
      const int k0 = ks * 32;
      half8 a[5], bf[2];
#pragma unroll
      for (int mt = 0; mt < 5; ++mt)
        a[mt] = *(const half8*)(w2f + (size_t)(ks * 40 + mt) * 512);
#pragma unroll
      for (int nt = 0; nt < 2; ++nt) {
        const int token = nt * 16 + l15;
        const unsigned byte = ((unsigned)(token * 2048 + (k0 + lq * 8) * 2))
                              ^ ((unsigned)(token & 7) << 4);
        bf[nt] = *(const half8*)(smem + byte);
      }
#pragma unroll
      for (int mt = 0; mt < 5; ++mt)
#pragma unroll
        for (int nt = 0; nt < 2; ++nt)
          acc[mt][nt] = __builtin_amdgcn_mfma_f32_16x16x32_f16(a[mt], bf[nt], acc[mt][nt], 0, 0, 0);
    }

    // per-lane top-2 (ascending code order -> first-index tie-break like np.argmax)
    float m1v[2] = {-1e30f,-1e30f};
    float m2v[2] = {-1e30f,-1e30f};
    unsigned i1v[2] = {0,0};
#pragma unroll
    for (int mt = 0; mt < 5; ++mt) {
      const int code0 = w * 80 + mt * 16 + lq * 4;   // global code 0..639
      const int cg0 = code0 - g * NC;                // in-group code 0..319
      const float4 b2v = *(const float4*)(b2 + code0);
#pragma unroll
      for (int nt = 0; nt < 2; ++nt) {
        const int tokg = T0 + nt * 16 + l15;
        const float4 gv = *(const float4*)(gum + ((size_t)tokg * 2 + g) * NC + cg0);
        const f32x4 v = acc[mt][nt];
        const float ss[4] = {v[0] + b2v.x + gv.x, v[1] + b2v.y + gv.y,
                             v[2] + b2v.z + gv.z, v[3] + b2v.w + gv.w};
#pragma unroll
        for (int r = 0; r < 4; ++r) {
          const float sv = ss[r];
          const unsigned cc = (unsigned)(cg0 + r);
          if (sv > m1v[nt]) { m2v[nt] = m1v[nt]; m1v[nt] = sv; i1v[nt] = cc; }
          else if (sv > m2v[nt]) m2v[nt] = sv;
        }
      }
    }
#pragma unroll
    for (int mask = 16; mask <= 32; mask <<= 1) {
#pragma unroll
      for (int nt = 0; nt < 2; ++nt) {
        const float om1 = __shfl_xor(m1v[nt], mask);
        const float om2 = __shfl_xor(m2v[nt], mask);
        const unsigned oi = (unsigned)__shfl_xor((int)i1v[nt], mask);
        const bool take = (om1 > m1v[nt]) || (om1 == m1v[nt] && oi < i1v[nt]);
        if (take) { m2v[nt] = fmaxf(m1v[nt], om2); m1v[nt] = om1; i1v[nt] = oi; }
        else      { m2v[nt] = fmaxf(m2v[nt], om1); }
      }
    }
    if (l < 16) {
#pragma unroll
      for (int nt = 0; nt < 2; ++nt) {
        const int tok = nt * 16 + l15;
        redm1[w * 32 + tok] = m1v[nt];
        redm2[w * 32 + tok] = m2v[nt];
        redi [w * 32 + tok] = i1v[nt];
      }
    }
  }
  __syncthreads();

  // ---- final combine across the 4 waves of each group; flag near-ties
  if (tid < 64) {
    const int pg = tid >> 5;
    const int tok = tid & 31;
    float m1 = -1e30f, m2 = -1e30f; unsigned i1 = 0;
#pragma unroll
    for (int k = 0; k < 4; ++k) {
      const int ww = pg * 4 + k;   // ascending code blocks -> ties keep lower code
      const float a1 = redm1[ww * 32 + tok];
      const float a2 = redm2[ww * 32 + tok];
      const unsigned ai = redi[ww * 32 + tok];
      if (a1 > m1) { m2 = fmaxf(m1, a2); m1 = a1; i1 = ai; }
      else         { m2 = fmaxf(m2, a1); }
    }
    idxs[tid] = i1;
    if (m1 - m2 < MARGIN) {
      const unsigned pos = atomicAdd(cnt, 1u);
      if (pos < RCAP) list[pos] = (unsigned)(((T0 + tok) << 1) | pg);
    }
  }
  __syncthreads();

  // ---- gather emb rows -> out (64 pairs x 128 floats; 32 lanes per pair)
#pragma unroll
  for (int i = 0; i < 4; ++i) {
    const int q = tid + i * 512;   // float4 index, 0..2047
    const int p = q >> 5;          // pair 0..63
    const int dd = q & 31;
    const int pg = p >> 5;
    const int tok = p & 31;
    const unsigned idx = idxs[p];
    *(float4*)(out + (size_t)(T0 + tok) * OUTD + pg * VD + dd * 4)
      = *(const float4*)(emb + (size_t)idx * VD + dd * 4);
  }
}

// ---------------------------------------------------------------- refine, stage 1:
__global__ __launch_bounds__(512, 4)
void refine1_kernel(const float* __restrict__ x, const float* __restrict__ W1,
                    const float* __restrict__ b1,
                    const unsigned* __restrict__ cnt, const unsigned* __restrict__ list,
                    float* __restrict__ hdws) {
  __shared__ float xs[DIM];
  unsigned n = cnt[0]; if (n > RCAP) n = RCAP;
  const unsigned e = blockIdx.x;
  if (e >= n) return;
  const unsigned tok = list[e] >> 1;
  const int tid = threadIdx.x;                 // 512 == DIM
  xs[tid] = x[(size_t)tok * DIM + tid];
  __syncthreads();

  double a0 = 0.0, a1 = 0.0, c0 = 0.0, c1 = 0.0;
#pragma unroll 4
  for (int k = 0; k < DIM; k += 2) {
    const double x0 = (double)xs[k], x1 = (double)xs[k + 1];
    const float* r0 = W1 + (size_t)k * INNER + tid;
    const float* r1 = W1 + (size_t)(k + 1) * INNER + tid;
    a0 += x0 * (double)r0[0];
    a1 += x0 * (double)r0[512];
    c0 += x1 * (double)r1[0];
    c1 += x1 * (double)r1[512];
  }
  const double s0 = a0 + c0 + (double)b1[tid];
  const double s1 = a1 + c1 + (double)b1[tid + 512];
  hdws[(size_t)e * INNER + tid]       = (float)(0.5 * s0 * (1.0 + erf(s0 * 0.70710678118654752440)));
  hdws[(size_t)e * INNER + tid + 512] = (float)(0.5 * s1 * (1.0 + erf(s1 * 0.70710678118654752440)));
}

// ---------------------------------------------------------------- refine, stage 2:
__global__ __launch_bounds__(320, 4)
void refine2_kernel(const float* __restrict__ gum, const float* __restrict__ W2,
                    const float* __restrict__ b2, const float* __restrict__ emb,
                    float* __restrict__ out,
                    const unsigned* __restrict__ cnt, const unsigned* __restrict__ list,
                    const float* __restrict__ hdws) {
  __shared__ float hs[INNER];
  __shared__ double wv[5];
  __shared__ int wi[5];
  __shared__ int best;
  unsigned n = cnt[0]; if (n > RCAP) n = RCAP;
  const unsigned e = blockIdx.x;
  if (e >= n) return;
  const unsigned tok = list[e] >> 1;
  const int g = (int)(list[e] & 1u);
  const int tid = threadIdx.x;                 // 320 threads, one code each

  for (int j = tid; j < INNER; j += 320) hs[j] = hdws[(size_t)e * INNER + j];
  __syncthreads();

  const float* w2c = W2 + (size_t)g * NC + tid;   // column, stride 640 floats
  double acc = 0.0, accb = 0.0;
#pragma unroll 4
  for (int k = 0; k < INNER; k += 2) {
    acc  += (double)hs[k]     * (double)w2c[(size_t)k * (NC * NGRP)];
    accb += (double)hs[k + 1] * (double)w2c[(size_t)(k + 1) * (NC * NGRP)];
  }
  double v = acc + accb + (double)b2[g * NC + tid]
                        + (double)gum[((size_t)tok * 2 + g) * NC + tid];
  int bi = tid;
#pragma unroll
  for (int m = 1; m < 64; m <<= 1) {
    const double ov = __shfl_xor(v, m);
    const int oi = __shfl_xor(bi, m);
    if (ov > v || (ov == v && oi < bi)) { v = ov; bi = oi; }
  }
  if ((tid & 63) == 0) { wv[tid >> 6] = v; wi[tid >> 6] = bi; }
  __syncthreads();
  if (tid == 0) {
    double bv = wv[0]; int bb = wi[0];
#pragma unroll
    for (int k = 1; k < 5; ++k)
      if (wv[k] > bv || (wv[k] == bv && wi[k] < bb)) { bv = wv[k]; bb = wi[k]; }
    best = bb;
  }
  __syncthreads();
  if (tid < VD)
    out[(size_t)tok * OUTD + g * VD + tid] = emb[(size_t)best * VD + tid];
}

// ---------------------------------------------------------------- refine fallback
__global__ __launch_bounds__(512, 1)
void refine_kernel(const float* __restrict__ x, const float* __restrict__ gum,
                   const float* __restrict__ W1, const float* __restrict__ b1,
                   const float* __restrict__ W2, const float* __restrict__ b2,
                   const float* __restrict__ emb, float* __restrict__ out,
                   const unsigned* __restrict__ cnt, const unsigned* __restrict__ list) {
  __shared__ double xs[4][DIM];
  __shared__ double hd[4][INNER];
  __shared__ double sc[4][NC];
  __shared__ int amax[4];
  const int tid = threadIdx.x;
  unsigned n = cnt[0];
  if (n > RCAP) n = RCAP;

  for (unsigned base = blockIdx.x * 4u; base < n; base += gridDim.x * 4u) {
    const int nb = (int)((n - base) < 4u ? (n - base) : 4u);
    unsigned ng[4];
#pragma unroll
    for (int e = 0; e < 4; ++e) ng[e] = list[base + (e < nb ? e : 0)];

    for (int e = 0; e < nb; ++e)
      xs[e][tid] = (double)x[(size_t)(ng[e] >> 1) * DIM + tid];
    __syncthreads();

#pragma unroll
    for (int jj = 0; jj < 2; ++jj) {
      const int j = tid + jj * 512;
      double a0 = 0, a1 = 0, a2 = 0, a3 = 0;
      for (int k = 0; k < DIM; ++k) {
        const double wvv = (double)W1[(size_t)k * INNER + j];
        a0 += xs[0][k] * wvv; a1 += xs[1][k] * wvv;
        a2 += xs[2][k] * wvv; a3 += xs[3][k] * wvv;
      }
      const double bb = (double)b1[j];
      const double s0 = a0 + bb, s1 = a1 + bb, s2 = a2 + bb, s3 = a3 + bb;
      hd[0][j] = 0.5 * s0 * (1.0 + erf(s0 * 0.70710678118654752440));
      hd[1][j] = 0.5 * s1 * (1.0 + erf(s1 * 0.70710678118654752440));
      hd[2][j] = 0.5 * s2 * (1.0 + erf(s2 * 0.70710678118654752440));
      hd[3][j] = 0.5 * s3 * (1.0 + erf(s3 * 0.70710678118654752440));
    }
    __syncthreads();

    for (int task = tid; task < 4 * NC; task += 512) {
      const int e = task / NC;
      const int c = task - e * NC;
      if (e < nb) {
        const unsigned tok = ng[e] >> 1;
        const int gg = (int)(ng[e] & 1u);
        const float* w2c = W2 + (size_t)gg * NC + c;
        double acc = 0.0;
        for (int k = 0; k < INNER; ++k)
          acc += hd[e][k] * (double)w2c[(size_t)k * (NC * NGRP)];
        sc[e][c] = acc + (double)b2[gg * NC + c]
                       + (double)gum[((size_t)tok * 2 + gg) * NC + c];
      }
    }
    __syncthreads();

    if (tid < 4 && tid < nb) {
      double bestv = sc[tid][0]; int bi = 0;
      for (int c = 1; c < NC; ++c)
        if (sc[tid][c] > bestv) { bestv = sc[tid][c]; bi = c; }
      amax[tid] = bi;
    }
    __syncthreads();

    {
      const int e = tid >> 7;
      const int d = tid & 127;
      if (e < nb) {
        const unsigned tok = ng[e] >> 1;
        const int gg = (int)(ng[e] & 1u);
        out[(size_t)tok * OUTD + gg * VD + d] = emb[(size_t)amax[e] * VD + d];
      }
    }
    __syncthreads();
  }
}

// ---------------------------------------------------------------- launch
extern "C" void kernel_launch(void* const* d_in, const int* in_sizes, int n_in,
                              void* d_out, int out_size, void* d_ws, size_t ws_size,
                              hipStream_t stream) {
  (void)in_sizes; (void)n_in; (void)out_size;
  const float* x   = (const float*)d_in[0];
  const float* gum = (const float*)d_in[1];
  const float* W1  = (const float*)d_in[2];
  const float* b1  = (const float*)d_in[3];
  const float* W2  = (const float*)d_in[4];
  const float* b2  = (const float*)d_in[5];
  const float* emb = (const float*)d_in[6];
  float* out = (float*)d_out;
  char* ws = (char*)d_ws;
  unsigned* cnt  = (unsigned*)ws;
  unsigned* list = (unsigned*)(ws + 16);
  _Float16* W1F = (_Float16*)(ws + W1F_OFF);
  _Float16* W2F = (_Float16*)(ws + W2F_OFF);
  float* hdws = (float*)(ws + HD_OFF);

  hipFuncSetAttribute((const void*)fused_kernel,
                      hipFuncAttributeMaxDynamicSharedMemorySize, SMEM_BYTES);

  const int prep_items = W1F_N + W2F_N;                 // 147456 half8's
  prep_kernel<<<(prep_items + 255) / 256, 256, 0, stream>>>(W1, W2, W1F, W2F, cnt);
  fused_kernel<<<NTOK / 32, 512, SMEM_BYTES, stream>>>(x, gum, W1F, W2F, b1, b2,
                                                       emb, out, cnt, list);
  const bool big_ws = ws_size >= (size_t)HD_OFF + (size_t)RCAP * INNER * sizeof(float);
  if (big_ws) {
    refine1_kernel<<<RCAP, 512, 0, stream>>>(x, W1, b1, cnt, list, hdws);
    refine2_kernel<<<RCAP, 320, 0, stream>>>(gum, W2, b2, emb, out, cnt, list, hdws);
  } else {
    refine_kernel<<<256, 512, 0, stream>>>(x, gum, W1, b1, W2, b2, emb, out, cnt, list);
  }
}